// Round 4
// baseline (660.665 us; speedup 1.0000x reference)
//
#include <hip/hip_runtime.h>

#define F 128
#define CLSN 40
#define NFINE_MAX 256
#define NSUP_MAX 25
#define KSPLIT 16
#define STAGE_CAP 10240

typedef __attribute__((ext_vector_type(8))) short short8v;
typedef __attribute__((ext_vector_type(4))) float float4v;

static __device__ inline ushort f2bf(float f) {
  uint u = __float_as_uint(f);
  uint r = (u + 0x7FFFu + ((u >> 16) & 1u)) >> 16;
  return (ushort)r;
}

// ---------------- casts / packing ----------------
__global__ __launch_bounds__(256) void k_cast(const float* __restrict__ in,
                                              ushort* __restrict__ outb, int nelem4) {
  int i = blockIdx.x * 256 + threadIdx.x;
  if (i < nelem4) {
    float4 v = reinterpret_cast<const float4*>(in)[i];
    ushort4 o;
    o.x = f2bf(v.x); o.y = f2bf(v.y); o.z = f2bf(v.z); o.w = f2bf(v.w);
    reinterpret_cast<ushort4*>(outb)[i] = o;
  }
}

__global__ __launch_bounds__(256) void k_pack_w1(const float* __restrict__ Wl,
                                                 const float* __restrict__ Wr,
                                                 ushort* __restrict__ Wp) {
  int t = blockIdx.x * 256 + threadIdx.x;
  if (t >= 4096) return;
  int lane = t & 63, f = (t >> 6) & 7, ks = t >> 9;
  int col = f * 16 + (lane & 15);
  int k0 = ks * 32 + (lane >> 4) * 8;
#pragma unroll
  for (int j = 0; j < 8; ++j) {
    int k = k0 + j;
    float w = (k < 128) ? Wl[k * 128 + col] : Wr[(k - 128) * 128 + col];
    Wp[t * 8 + j] = f2bf(w);
  }
}

__global__ __launch_bounds__(256) void k_pack_w2(const float* __restrict__ Wl,
                                                 const float* __restrict__ Wr,
                                                 ushort* __restrict__ Wp) {
  int t = blockIdx.x * 256 + threadIdx.x;
  if (t >= 1536) return;
  int lane = t & 63, rem = t >> 6;
  int f = rem % 3, ks = rem / 3;
  int col = f * 16 + (lane & 15);
  int k0 = ks * 32 + (lane >> 4) * 8;
#pragma unroll
  for (int j = 0; j < 8; ++j) {
    int k = k0 + j;
    float w = 0.f;
    if (col < CLSN) w = (k < 128) ? Wl[k * CLSN + col] : Wr[(k - 128) * CLSN + col];
    Wp[t * 8 + j] = f2bf(w);
  }
}

// ---------------- binned CSR build ----------------
// fine bucket = dst>>9 (512 nodes); super bucket = dst>>12 (4096 nodes, 8 fine each)

__global__ __launch_bounds__(256) void k_hist(const int* __restrict__ dst,
                                              int* __restrict__ hist, int E, int nfine) {
  __shared__ int hh[NFINE_MAX];
  for (int i = threadIdx.x; i < NFINE_MAX; i += 256) hh[i] = 0;
  __syncthreads();
  int stride = gridDim.x * 256;
  int nq = E >> 2;
  for (int i = blockIdx.x * 256 + threadIdx.x; i < nq; i += stride) {
    int4 d = reinterpret_cast<const int4*>(dst)[i];
    atomicAdd(&hh[d.x >> 9], 1);
    atomicAdd(&hh[d.y >> 9], 1);
    atomicAdd(&hh[d.z >> 9], 1);
    atomicAdd(&hh[d.w >> 9], 1);
  }
  if (blockIdx.x == 0) {
    for (int e = (E & ~3) + threadIdx.x; e < E; e += 256) atomicAdd(&hh[dst[e] >> 9], 1);
  }
  __syncthreads();
  for (int i = threadIdx.x; i < nfine; i += 256)
    if (hh[i]) atomicAdd(&hist[i], hh[i]);
}

// single block: scan fine hist -> fbase/fcur; super bases -> sbase/scur
__global__ __launch_bounds__(256) void k_scan_bases(const int* __restrict__ hist,
                                                    int* __restrict__ fbase,
                                                    int* __restrict__ fcur,
                                                    int* __restrict__ sbase,
                                                    int* __restrict__ scur,
                                                    int nfine, int nsup, int E) {
  __shared__ int s[256];
  int tid = threadIdx.x;
  int v = (tid < nfine) ? hist[tid] : 0;
  s[tid] = v;
  __syncthreads();
  for (int d = 1; d < 256; d <<= 1) {
    int u = (tid >= d) ? s[tid - d] : 0;
    __syncthreads();
    s[tid] += u;
    __syncthreads();
  }
  if (tid < nfine) {
    int excl = s[tid] - v;
    fbase[tid] = excl;
    fcur[tid] = excl;
  }
  if (tid == 0) fbase[nfine] = E;
  if (tid <= nsup) {
    int idx = tid * 8;
    int sb = (idx >= nfine) ? E : (s[idx] - hist[idx]);
    sbase[tid] = sb;
    if (tid < nsup) scur[tid] = sb;
  }
}

// level-1 bin: edges -> super buckets. packed = src(17b) | dstlow12 << 17
__global__ __launch_bounds__(256) void k_bin1(const int* __restrict__ src,
                                              const int* __restrict__ dst,
                                              int* __restrict__ scur,
                                              uint* __restrict__ pairs1, int E) {
  __shared__ int s_cnt[4][NSUP_MAX];
  __shared__ uint s_stage[4][NSUP_MAX][64];
  const int tid = threadIdx.x, w = tid >> 6, lane = tid & 63;
  for (int i = lane; i < NSUP_MAX; i += 64) s_cnt[w][i] = 0;
  const int gw = blockIdx.x * 4 + w;
  const int nw = gridDim.x * 4;
  for (int base = gw * 64; base < E; base += nw * 64) {
    int e = base + lane;
    bool valid = e < E;
    int sv = 0, dv = 0;
    if (valid) { sv = src[e]; dv = dst[e]; }
    int bb_my = dv >> 12;
    uint packed = (uint)sv | ((uint)(dv & 4095) << 17);
    unsigned long long rem = __ballot(valid);
    while (rem) {
      int leader = __ffsll((long long)rem) - 1;
      int bsel = __shfl(bb_my, leader);
      unsigned long long same = __ballot(bb_my == bsel) & rem;
      rem &= ~same;
      bool mine = (same >> lane) & 1ULL;
      int rank = __popcll(same & ((1ULL << lane) - 1ULL));
      int total = __popcll(same);
      int cur = s_cnt[w][bsel];
      int pos = cur + rank;
      if (mine && pos < 64) s_stage[w][bsel][pos] = packed;
      int remn = cur + total;
      if (remn >= 64) {
        int gbase = 0;
        if (lane == 0) gbase = atomicAdd(&scur[bsel], 64);
        gbase = __shfl(gbase, 0);
        pairs1[gbase + lane] = s_stage[w][bsel][lane];
        pos -= 64;
        if (mine && pos >= 0) s_stage[w][bsel][pos] = packed;
        remn -= 64;
      }
      if (lane == 0) s_cnt[w][bsel] = remn;
    }
  }
  // tail flush: wave-cooperative, contiguous runs
  for (int bb = 0; bb < NSUP_MAX; ++bb) {
    int c = s_cnt[w][bb];
    if (c > 0) {
      int gbase = 0;
      if (lane == 0) gbase = atomicAdd(&scur[bb], c);
      gbase = __shfl(gbase, 0);
      if (lane < c) pairs1[gbase + lane] = s_stage[w][bb][lane];
    }
  }
}

// level-2 bin: super bucket -> its 8 fine buckets. repack = src | dstlow9 << 17
__global__ __launch_bounds__(256) void k_bin2(const uint* __restrict__ pairs1,
                                              const int* __restrict__ sbase,
                                              int* __restrict__ fcur,
                                              uint* __restrict__ pairs2) {
  __shared__ int s_cnt[4][8];
  __shared__ uint s_stage[4][8][64];
  const int tid = threadIdx.x, w = tid >> 6, lane = tid & 63;
  const int sb = blockIdx.x / KSPLIT, slice = blockIdx.x % KSPLIT;
  const int beg = sbase[sb], end = sbase[sb + 1];
  const int len = end - beg;
  const int a0 = beg + (int)((long long)len * slice / KSPLIT);
  const int a1 = beg + (int)((long long)len * (slice + 1) / KSPLIT);
  if (lane < 8) s_cnt[w][lane] = 0;
  const int fgbase = sb * 8;
  for (int base = a0 + w * 64; base < a1; base += 4 * 64) {
    int e = base + lane;
    bool valid = e < a1;
    uint p = valid ? pairs1[e] : 0u;
    int d12 = (int)(p >> 17);
    int f_my = d12 >> 9;  // 0..7
    uint packed = (p & 0x1FFFFu) | ((uint)(d12 & 511) << 17);
    unsigned long long rem = __ballot(valid);
    while (rem) {
      int leader = __ffsll((long long)rem) - 1;
      int fsel = __shfl(f_my, leader);
      unsigned long long same = __ballot(f_my == fsel) & rem;
      rem &= ~same;
      bool mine = (same >> lane) & 1ULL;
      int rank = __popcll(same & ((1ULL << lane) - 1ULL));
      int total = __popcll(same);
      int cur = s_cnt[w][fsel];
      int pos = cur + rank;
      if (mine && pos < 64) s_stage[w][fsel][pos] = packed;
      int remn = cur + total;
      if (remn >= 64) {
        int gbase = 0;
        if (lane == 0) gbase = atomicAdd(&fcur[fgbase + fsel], 64);
        gbase = __shfl(gbase, 0);
        pairs2[gbase + lane] = s_stage[w][fsel][lane];
        pos -= 64;
        if (mine && pos >= 0) s_stage[w][fsel][pos] = packed;
        remn -= 64;
      }
      if (lane == 0) s_cnt[w][fsel] = remn;
    }
  }
  for (int f = 0; f < 8; ++f) {
    int c = s_cnt[w][f];
    if (c > 0) {
      int gbase = 0;
      if (lane == 0) gbase = atomicAdd(&fcur[fgbase + f], c);
      gbase = __shfl(gbase, 0);
      if (lane < c) pairs2[gbase + lane] = s_stage[w][f][lane];
    }
  }
}

// level-3: one block per fine bucket; local hist+scan (emits offsets), LDS-staged
// CSR scatter, sequential full-line srcs flush.
__global__ __launch_bounds__(256) void k_local_scatter(const uint* __restrict__ pairs2,
                                                       const int* __restrict__ fbase,
                                                       int* __restrict__ offsets,
                                                       int* __restrict__ srcs,
                                                       int n, int E) {
  __shared__ int s_cnt[512];
  __shared__ int s_scan[512];
  __shared__ int s_stage[STAGE_CAP];
  const int b = blockIdx.x, tid = threadIdx.x;
  const int node0 = b << 9;
  const int ebase = fbase[b], eend = fbase[b + 1];
  const int ecnt = eend - ebase;
  s_cnt[tid] = 0;
  s_cnt[tid + 256] = 0;
  __syncthreads();
  for (int i = tid; i < ecnt; i += 256) atomicAdd(&s_cnt[pairs2[ebase + i] >> 17], 1);
  __syncthreads();
  s_scan[tid] = s_cnt[tid];
  s_scan[tid + 256] = s_cnt[tid + 256];
  __syncthreads();
  for (int d = 1; d < 512; d <<= 1) {
    int v0 = (tid >= d) ? s_scan[tid - d] : 0;
    int v1 = (tid + 256 >= d) ? s_scan[tid + 256 - d] : 0;
    __syncthreads();
    s_scan[tid] += v0;
    s_scan[tid + 256] += v1;
    __syncthreads();
  }
  int e0 = s_scan[tid] - s_cnt[tid];
  int e1 = s_scan[tid + 256] - s_cnt[tid + 256];
  if (node0 + tid < n) offsets[node0 + tid] = ebase + e0;
  if (node0 + tid + 256 < n) offsets[node0 + tid + 256] = ebase + e1;
  if (b == gridDim.x - 1 && tid == 0) offsets[n] = E;
  __syncthreads();
  s_cnt[tid] = e0;  // reuse as local cursor
  s_cnt[tid + 256] = e1;
  __syncthreads();
  for (int i = tid; i < ecnt; i += 256) {
    uint p = pairs2[ebase + i];
    int v = (int)(p >> 17);
    int s = (int)(p & 0x1FFFFu);
    int pos = atomicAdd(&s_cnt[v], 1);
    if (pos < STAGE_CAP) s_stage[pos] = s;
    else srcs[ebase + pos] = s;  // overflow guard (statistically never)
  }
  __syncthreads();
  int lim = min(ecnt, STAGE_CAP);
  for (int i = tid; i < lim; i += 256) srcs[ebase + i] = s_stage[i];
}

// ---------------- mean aggregation (bf16 in, bf16 out, fp32 accum) ----------------
__global__ __launch_bounds__(256) void k_aggregate(const ushort* __restrict__ feat,
                                                   const int* __restrict__ offsets,
                                                   const int* __restrict__ srcs,
                                                   ushort* __restrict__ mean, int n) {
  int gw = (blockIdx.x * 256 + threadIdx.x) >> 6;
  int lane = threadIdx.x & 63;
  if (gw >= n) return;
  const uint* fp = reinterpret_cast<const uint*>(feat);
  int beg = offsets[gw], end = offsets[gw + 1];
  float ax = 0.f, ay = 0.f;
  for (int chunk = beg; chunk < end; chunk += 64) {
    int cnt = min(64, end - chunk);
    int s = (lane < cnt) ? srcs[chunk + lane] : 0;
    int k = 0;
    for (; k + 7 < cnt; k += 8) {
      int s0 = __shfl(s, k), s1 = __shfl(s, k + 1);
      int s2 = __shfl(s, k + 2), s3 = __shfl(s, k + 3);
      int s4 = __shfl(s, k + 4), s5 = __shfl(s, k + 5);
      int s6 = __shfl(s, k + 6), s7 = __shfl(s, k + 7);
      uint u0 = fp[(size_t)s0 * 64 + lane];
      uint u1 = fp[(size_t)s1 * 64 + lane];
      uint u2 = fp[(size_t)s2 * 64 + lane];
      uint u3 = fp[(size_t)s3 * 64 + lane];
      uint u4 = fp[(size_t)s4 * 64 + lane];
      uint u5 = fp[(size_t)s5 * 64 + lane];
      uint u6 = fp[(size_t)s6 * 64 + lane];
      uint u7 = fp[(size_t)s7 * 64 + lane];
      ax += __uint_as_float(u0 << 16) + __uint_as_float(u1 << 16) +
            __uint_as_float(u2 << 16) + __uint_as_float(u3 << 16) +
            __uint_as_float(u4 << 16) + __uint_as_float(u5 << 16) +
            __uint_as_float(u6 << 16) + __uint_as_float(u7 << 16);
      ay += __uint_as_float(u0 & 0xFFFF0000u) + __uint_as_float(u1 & 0xFFFF0000u) +
            __uint_as_float(u2 & 0xFFFF0000u) + __uint_as_float(u3 & 0xFFFF0000u) +
            __uint_as_float(u4 & 0xFFFF0000u) + __uint_as_float(u5 & 0xFFFF0000u) +
            __uint_as_float(u6 & 0xFFFF0000u) + __uint_as_float(u7 & 0xFFFF0000u);
    }
    for (; k < cnt; ++k) {
      int s0 = __shfl(s, k);
      uint u0 = fp[(size_t)s0 * 64 + lane];
      ax += __uint_as_float(u0 << 16);
      ay += __uint_as_float(u0 & 0xFFFF0000u);
    }
  }
  int dg = end - beg;
  float inv = dg > 0 ? 1.f / (float)dg : 0.f;
  uint lo = f2bf(ax * inv), hi = f2bf(ay * inv);
  reinterpret_cast<uint*>(mean)[(size_t)gw * 64 + lane] = lo | (hi << 16);
}

// ---------------- layer1 MFMA GEMM: h = relu([mean|x]@Wp1 + b1), bf16 out ------------
__global__ __launch_bounds__(256) void k_mfma1(const ushort* __restrict__ meanb,
                                               const ushort* __restrict__ rootb,
                                               const ushort* __restrict__ Wp,
                                               const float* __restrict__ b,
                                               ushort* __restrict__ h, int nrows) {
  __shared__ __align__(16) ushort As[64 * 256];  // 32KB, XOR-swizzled
  const int tid = threadIdx.x;
  const int row0 = blockIdx.x * 64;
#pragma unroll
  for (int i = 0; i < 8; ++i) {
    int c = tid + i * 256;
    int r = c >> 5;
    int c16 = c & 31;
    int grow = row0 + r;
    short8v v = {0, 0, 0, 0, 0, 0, 0, 0};
    if (grow < nrows) {
      const ushort* srcp = (c16 < 16) ? (meanb + (size_t)grow * 128 + c16 * 8)
                                      : (rootb + (size_t)grow * 128 + (c16 - 16) * 8);
      v = *reinterpret_cast<const short8v*>(srcp);
    }
    int dbyte = r * 512 + ((c16 * 16) ^ ((r & 7) << 4));
    *reinterpret_cast<short8v*>(reinterpret_cast<char*>(As) + dbyte) = v;
  }
  __syncthreads();
  const int lane = tid & 63;
  const int rbase = (tid >> 6) * 16;
  const int arow = rbase + (lane & 15);
  const int axor = (arow & 7) << 4;
  const short8v* Wp8 = reinterpret_cast<const short8v*>(Wp);
  float4v acc[8];
#pragma unroll
  for (int f = 0; f < 8; ++f) acc[f] = {0.f, 0.f, 0.f, 0.f};
#pragma unroll
  for (int ks = 0; ks < 8; ++ks) {
    int abyte = arow * 512 + ((ks * 64 + (lane >> 4) * 16) ^ axor);
    short8v a = *reinterpret_cast<const short8v*>(reinterpret_cast<const char*>(As) + abyte);
#pragma unroll
    for (int f = 0; f < 8; ++f) {
      short8v bf = Wp8[(ks * 8 + f) * 64 + lane];
      acc[f] = __builtin_amdgcn_mfma_f32_16x16x32_bf16(a, bf, acc[f], 0, 0, 0);
    }
  }
  const int col_lo = lane & 15;
  const int rq = (lane >> 4) * 4;
#pragma unroll
  for (int f = 0; f < 8; ++f) {
    int col = f * 16 + col_lo;
    float bias = b[col];
#pragma unroll
    for (int r = 0; r < 4; ++r) {
      int row = row0 + rbase + rq + r;
      if (row < nrows) {
        float vv = fmaxf(acc[f][r] + bias, 0.f);
        h[(size_t)row * 128 + col] = f2bf(vv);
      }
    }
  }
}

// ---------------- layer2 MFMA GEMM: out = [mean2|h]@Wp2 + b2, fp32 out ----------------
__global__ __launch_bounds__(256) void k_mfma2(const ushort* __restrict__ meanb,
                                               const ushort* __restrict__ rootb,
                                               const ushort* __restrict__ Wp,
                                               const float* __restrict__ b,
                                               float* __restrict__ out, int nrows) {
  __shared__ __align__(16) ushort As[64 * 256];
  const int tid = threadIdx.x;
  const int row0 = blockIdx.x * 64;
#pragma unroll
  for (int i = 0; i < 8; ++i) {
    int c = tid + i * 256;
    int r = c >> 5;
    int c16 = c & 31;
    int grow = row0 + r;
    short8v v = {0, 0, 0, 0, 0, 0, 0, 0};
    if (grow < nrows) {
      const ushort* srcp = (c16 < 16) ? (meanb + (size_t)grow * 128 + c16 * 8)
                                      : (rootb + (size_t)grow * 128 + (c16 - 16) * 8);
      v = *reinterpret_cast<const short8v*>(srcp);
    }
    int dbyte = r * 512 + ((c16 * 16) ^ ((r & 7) << 4));
    *reinterpret_cast<short8v*>(reinterpret_cast<char*>(As) + dbyte) = v;
  }
  __syncthreads();
  const int lane = tid & 63;
  const int rbase = (tid >> 6) * 16;
  const int arow = rbase + (lane & 15);
  const int axor = (arow & 7) << 4;
  const short8v* Wp8 = reinterpret_cast<const short8v*>(Wp);
  float4v acc[3];
#pragma unroll
  for (int f = 0; f < 3; ++f) acc[f] = {0.f, 0.f, 0.f, 0.f};
#pragma unroll
  for (int ks = 0; ks < 8; ++ks) {
    int abyte = arow * 512 + ((ks * 64 + (lane >> 4) * 16) ^ axor);
    short8v a = *reinterpret_cast<const short8v*>(reinterpret_cast<const char*>(As) + abyte);
#pragma unroll
    for (int f = 0; f < 3; ++f) {
      short8v bf = Wp8[(ks * 3 + f) * 64 + lane];
      acc[f] = __builtin_amdgcn_mfma_f32_16x16x32_bf16(a, bf, acc[f], 0, 0, 0);
    }
  }
  const int col_lo = lane & 15;
  const int rq = (lane >> 4) * 4;
#pragma unroll
  for (int f = 0; f < 3; ++f) {
    int col = f * 16 + col_lo;
    if (col < CLSN) {
      float bias = b[col];
#pragma unroll
      for (int r = 0; r < 4; ++r) {
        int row = row0 + rbase + rq + r;
        if (row < nrows) out[(size_t)row * CLSN + col] = acc[f][r] + bias;
      }
    }
  }
}

extern "C" void kernel_launch(void* const* d_in, const int* in_sizes, int n_in,
                              void* d_out, int out_size, void* d_ws, size_t ws_size,
                              hipStream_t stream) {
  const float* x = (const float*)d_in[0];
  const int* ei = (const int*)d_in[1];
  const float* Wl1 = (const float*)d_in[2];
  const float* Wr1 = (const float*)d_in[3];
  const float* b1 = (const float*)d_in[4];
  const float* Wl2 = (const float*)d_in[5];
  const float* Wr2 = (const float*)d_in[6];
  const float* b2 = (const float*)d_in[7];
  float* out = (float*)d_out;

  const int n = in_sizes[0] / F;
  const int E = in_sizes[1] / 2;
  const int* src = ei;
  const int* dst = ei + E;

  const int nfine = (n + 511) >> 9;   // 196
  const int nsup = (nfine + 7) >> 3;  // 25

  size_t off = 0;
  auto alloc = [&](size_t bytes) {
    size_t cur = off;
    off = (off + bytes + 255) & ~(size_t)255;
    return cur;
  };
  char* w = (char*)d_ws;
  int* offsets = (int*)(w + alloc((size_t)(n + 1) * 4));
  int* srcs = (int*)(w + alloc((size_t)E * 4));
  int* hist = (int*)(w + alloc(NFINE_MAX * 4));
  int* fbase = (int*)(w + alloc((NFINE_MAX + 1) * 4));
  int* fcur = (int*)(w + alloc(NFINE_MAX * 4));
  int* sbase = (int*)(w + alloc(32 * 4));
  int* scur = (int*)(w + alloc(32 * 4));
  ushort* xb = (ushort*)(w + alloc((size_t)n * F * 2));
  ushort* hb = (ushort*)(w + alloc((size_t)n * F * 2));
  ushort* meanb = (ushort*)(w + alloc((size_t)n * F * 2));
  ushort* Wp1 = (ushort*)(w + alloc(32768 * 2));
  ushort* Wp2 = (ushort*)(w + alloc(12288 * 2));
  (void)ws_size;
  // pairs1/pairs2 alias meanb (dead before any aggregate runs)
  uint* pairs1 = (uint*)meanb;
  uint* pairs2 = (uint*)((char*)meanb + (((size_t)E * 4 + 255) & ~(size_t)255));

  // casts / weight packing
  k_cast<<<(n * 32 + 255) / 256, 256, 0, stream>>>(x, xb, n * 32);
  k_pack_w1<<<16, 256, 0, stream>>>(Wl1, Wr1, Wp1);
  k_pack_w2<<<6, 256, 0, stream>>>(Wl2, Wr2, Wp2);

  // binned CSR build
  hipMemsetAsync(hist, 0, NFINE_MAX * 4, stream);
  k_hist<<<256, 256, 0, stream>>>(dst, hist, E, nfine);
  k_scan_bases<<<1, 256, 0, stream>>>(hist, fbase, fcur, sbase, scur, nfine, nsup, E);
  k_bin1<<<160, 256, 0, stream>>>(src, dst, scur, pairs1, E);
  k_bin2<<<nsup * KSPLIT, 256, 0, stream>>>(pairs1, sbase, fcur, pairs2);
  k_local_scatter<<<nfine, 256, 0, stream>>>(pairs2, fbase, offsets, srcs, n, E);

  // layer 1
  k_aggregate<<<(n * 64 + 255) / 256, 256, 0, stream>>>(xb, offsets, srcs, meanb, n);
  k_mfma1<<<(n + 63) / 64, 256, 0, stream>>>(meanb, xb, Wp1, b1, hb, n);

  // layer 2
  k_aggregate<<<(n * 64 + 255) / 256, 256, 0, stream>>>(hb, offsets, srcs, meanb, n);
  k_mfma2<<<(n + 63) / 64, 256, 0, stream>>>(meanb, hb, Wp2, b2, out, n);
}

// Round 5
// 236.604 us; speedup vs baseline: 2.7923x; 2.7923x over previous
//
#include <hip/hip_runtime.h>

#define F 128
#define CLSN 40
#define NFINE_MAX 256
#define PCAP 10240
#define TILE 4096
#define STAGE_CAP 10240

typedef __attribute__((ext_vector_type(8))) short short8v;
typedef __attribute__((ext_vector_type(4))) float float4v;

static __device__ inline ushort f2bf(float f) {
  uint u = __float_as_uint(f);
  uint r = (u + 0x7FFFu + ((u >> 16) & 1u)) >> 16;
  return (ushort)r;
}

// ---------------- casts / packing ----------------
__global__ __launch_bounds__(256) void k_cast(const float* __restrict__ in,
                                              ushort* __restrict__ outb, int nelem4) {
  int i = blockIdx.x * 256 + threadIdx.x;
  if (i < nelem4) {
    float4 v = reinterpret_cast<const float4*>(in)[i];
    ushort4 o;
    o.x = f2bf(v.x); o.y = f2bf(v.y); o.z = f2bf(v.z); o.w = f2bf(v.w);
    reinterpret_cast<ushort4*>(outb)[i] = o;
  }
}

__global__ __launch_bounds__(256) void k_pack_w1(const float* __restrict__ Wl,
                                                 const float* __restrict__ Wr,
                                                 ushort* __restrict__ Wp) {
  int t = blockIdx.x * 256 + threadIdx.x;
  if (t >= 4096) return;
  int lane = t & 63, f = (t >> 6) & 7, ks = t >> 9;
  int col = f * 16 + (lane & 15);
  int k0 = ks * 32 + (lane >> 4) * 8;
#pragma unroll
  for (int j = 0; j < 8; ++j) {
    int k = k0 + j;
    float w = (k < 128) ? Wl[k * 128 + col] : Wr[(k - 128) * 128 + col];
    Wp[t * 8 + j] = f2bf(w);
  }
}

__global__ __launch_bounds__(256) void k_pack_w2(const float* __restrict__ Wl,
                                                 const float* __restrict__ Wr,
                                                 ushort* __restrict__ Wp) {
  int t = blockIdx.x * 256 + threadIdx.x;
  if (t >= 1536) return;
  int lane = t & 63, rem = t >> 6;
  int f = rem % 3, ks = rem / 3;
  int col = f * 16 + (lane & 15);
  int k0 = ks * 32 + (lane >> 4) * 8;
#pragma unroll
  for (int j = 0; j < 8; ++j) {
    int k = k0 + j;
    float w = 0.f;
    if (col < CLSN) w = (k < 128) ? Wl[k * CLSN + col] : Wr[(k - 128) * CLSN + col];
    Wp[t * 8 + j] = f2bf(w);
  }
}

// ---------------- one-pass tiled radix partition into fine buckets ----------------
// fine bucket b = dst>>9 (512 nodes). pairs region for bucket b: [b*PCAP, b*PCAP+cnt).
// packed entry: src (17b) | (dst&511) << 17.

__global__ void k_init_fcur(int* __restrict__ fcur, int nfine) {
  int i = blockIdx.x * 256 + threadIdx.x;
  if (i < nfine) fcur[i] = i * PCAP;
}

__global__ __launch_bounds__(256) void k_partition(const int* __restrict__ src,
                                                   const int* __restrict__ dst,
                                                   int* __restrict__ fcur,
                                                   uint* __restrict__ pairs, int E) {
  __shared__ int hh[NFINE_MAX];
  __shared__ int bb[NFINE_MAX];
  __shared__ unsigned char ebkt[TILE];
  __shared__ ushort dlow[TILE];
  const int tid = threadIdx.x;
  const int tile0 = blockIdx.x * TILE;
  const int lim = min(TILE, E - tile0);
  for (int i = tid; i < NFINE_MAX; i += 256) hh[i] = 0;
  __syncthreads();
  for (int i = tid; i < lim; i += 256) {
    int d = dst[tile0 + i];
    int b = d >> 9;
    ebkt[i] = (unsigned char)b;
    dlow[i] = (ushort)(d & 511);
    atomicAdd(&hh[b], 1);
  }
  __syncthreads();
  for (int i = tid; i < NFINE_MAX; i += 256) {
    int c = hh[i];
    bb[i] = c ? atomicAdd(&fcur[i], c) : 0;
    hh[i] = 0;  // reuse as local cursor
  }
  __syncthreads();
  for (int i = tid; i < lim; i += 256) {
    int b = ebkt[i];
    int r = atomicAdd(&hh[b], 1);
    uint p = (uint)src[tile0 + i] | ((uint)dlow[i] << 17);
    pairs[bb[b] + r] = p;
  }
}

// single block: bucket counts -> exclusive prefix fbase; fbase[nfine] = E
__global__ __launch_bounds__(256) void k_scan_fine(const int* __restrict__ fcur,
                                                   int* __restrict__ fbase,
                                                   int nfine, int E) {
  __shared__ int s[256];
  int tid = threadIdx.x;
  int v = (tid < nfine) ? (fcur[tid] - tid * PCAP) : 0;
  s[tid] = v;
  __syncthreads();
  for (int d = 1; d < 256; d <<= 1) {
    int u = (tid >= d) ? s[tid - d] : 0;
    __syncthreads();
    s[tid] += u;
    __syncthreads();
  }
  if (tid < nfine) fbase[tid] = s[tid] - v;
  if (tid == 0) fbase[nfine] = E;
}

// one block per fine bucket: local hist+scan (emits offsets), LDS-staged CSR
// scatter, sequential full-line srcs flush.
__global__ __launch_bounds__(256) void k_local_scatter(const uint* __restrict__ pairs,
                                                       const int* __restrict__ fcur,
                                                       const int* __restrict__ fbase,
                                                       int* __restrict__ offsets,
                                                       int* __restrict__ srcs,
                                                       int n, int E) {
  __shared__ int s_cnt[512];
  __shared__ int s_scan[512];
  __shared__ int s_stage[STAGE_CAP];
  const int b = blockIdx.x, tid = threadIdx.x;
  const int node0 = b << 9;
  const int pbase = b * PCAP;
  const int ebase = fbase[b];
  const int ecnt = fcur[b] - pbase;
  s_cnt[tid] = 0;
  s_cnt[tid + 256] = 0;
  __syncthreads();
  for (int i = tid; i < ecnt; i += 256) atomicAdd(&s_cnt[pairs[pbase + i] >> 17], 1);
  __syncthreads();
  s_scan[tid] = s_cnt[tid];
  s_scan[tid + 256] = s_cnt[tid + 256];
  __syncthreads();
  for (int d = 1; d < 512; d <<= 1) {
    int v0 = (tid >= d) ? s_scan[tid - d] : 0;
    int v1 = (tid + 256 >= d) ? s_scan[tid + 256 - d] : 0;
    __syncthreads();
    s_scan[tid] += v0;
    s_scan[tid + 256] += v1;
    __syncthreads();
  }
  int e0 = s_scan[tid] - s_cnt[tid];
  int e1 = s_scan[tid + 256] - s_cnt[tid + 256];
  if (node0 + tid < n) offsets[node0 + tid] = ebase + e0;
  if (node0 + tid + 256 < n) offsets[node0 + tid + 256] = ebase + e1;
  if (b == gridDim.x - 1 && tid == 0) offsets[n] = E;
  __syncthreads();
  s_cnt[tid] = e0;  // reuse as local cursor
  s_cnt[tid + 256] = e1;
  __syncthreads();
  for (int i = tid; i < ecnt; i += 256) {
    uint p = pairs[pbase + i];
    int v = (int)(p >> 17);
    int s = (int)(p & 0x1FFFFu);
    int pos = atomicAdd(&s_cnt[v], 1);
    if (pos < STAGE_CAP) s_stage[pos] = s;
    else srcs[ebase + pos] = s;  // overflow guard (statistically never)
  }
  __syncthreads();
  int lim = min(ecnt, STAGE_CAP);
  for (int i = tid; i < lim; i += 256) srcs[ebase + i] = s_stage[i];
}

// ---------------- mean aggregation (bf16 in, bf16 out, fp32 accum) ----------------
__global__ __launch_bounds__(256) void k_aggregate(const ushort* __restrict__ feat,
                                                   const int* __restrict__ offsets,
                                                   const int* __restrict__ srcs,
                                                   ushort* __restrict__ mean, int n) {
  int gw = (blockIdx.x * 256 + threadIdx.x) >> 6;
  int lane = threadIdx.x & 63;
  if (gw >= n) return;
  const uint* fp = reinterpret_cast<const uint*>(feat);
  int beg = offsets[gw], end = offsets[gw + 1];
  float ax = 0.f, ay = 0.f;
  for (int chunk = beg; chunk < end; chunk += 64) {
    int cnt = min(64, end - chunk);
    int s = (lane < cnt) ? srcs[chunk + lane] : 0;
    int k = 0;
    for (; k + 7 < cnt; k += 8) {
      int s0 = __shfl(s, k), s1 = __shfl(s, k + 1);
      int s2 = __shfl(s, k + 2), s3 = __shfl(s, k + 3);
      int s4 = __shfl(s, k + 4), s5 = __shfl(s, k + 5);
      int s6 = __shfl(s, k + 6), s7 = __shfl(s, k + 7);
      uint u0 = fp[(size_t)s0 * 64 + lane];
      uint u1 = fp[(size_t)s1 * 64 + lane];
      uint u2 = fp[(size_t)s2 * 64 + lane];
      uint u3 = fp[(size_t)s3 * 64 + lane];
      uint u4 = fp[(size_t)s4 * 64 + lane];
      uint u5 = fp[(size_t)s5 * 64 + lane];
      uint u6 = fp[(size_t)s6 * 64 + lane];
      uint u7 = fp[(size_t)s7 * 64 + lane];
      ax += __uint_as_float(u0 << 16) + __uint_as_float(u1 << 16) +
            __uint_as_float(u2 << 16) + __uint_as_float(u3 << 16) +
            __uint_as_float(u4 << 16) + __uint_as_float(u5 << 16) +
            __uint_as_float(u6 << 16) + __uint_as_float(u7 << 16);
      ay += __uint_as_float(u0 & 0xFFFF0000u) + __uint_as_float(u1 & 0xFFFF0000u) +
            __uint_as_float(u2 & 0xFFFF0000u) + __uint_as_float(u3 & 0xFFFF0000u) +
            __uint_as_float(u4 & 0xFFFF0000u) + __uint_as_float(u5 & 0xFFFF0000u) +
            __uint_as_float(u6 & 0xFFFF0000u) + __uint_as_float(u7 & 0xFFFF0000u);
    }
    for (; k < cnt; ++k) {
      int s0 = __shfl(s, k);
      uint u0 = fp[(size_t)s0 * 64 + lane];
      ax += __uint_as_float(u0 << 16);
      ay += __uint_as_float(u0 & 0xFFFF0000u);
    }
  }
  int dg = end - beg;
  float inv = dg > 0 ? 1.f / (float)dg : 0.f;
  uint lo = f2bf(ax * inv), hi = f2bf(ay * inv);
  reinterpret_cast<uint*>(mean)[(size_t)gw * 64 + lane] = lo | (hi << 16);
}

// ---------------- layer1 MFMA GEMM: h = relu([mean|x]@Wp1 + b1), bf16 out ------------
__global__ __launch_bounds__(256) void k_mfma1(const ushort* __restrict__ meanb,
                                               const ushort* __restrict__ rootb,
                                               const ushort* __restrict__ Wp,
                                               const float* __restrict__ b,
                                               ushort* __restrict__ h, int nrows) {
  __shared__ __align__(16) ushort As[64 * 256];  // 32KB, XOR-swizzled
  const int tid = threadIdx.x;
  const int row0 = blockIdx.x * 64;
#pragma unroll
  for (int i = 0; i < 8; ++i) {
    int c = tid + i * 256;
    int r = c >> 5;
    int c16 = c & 31;
    int grow = row0 + r;
    short8v v = {0, 0, 0, 0, 0, 0, 0, 0};
    if (grow < nrows) {
      const ushort* srcp = (c16 < 16) ? (meanb + (size_t)grow * 128 + c16 * 8)
                                      : (rootb + (size_t)grow * 128 + (c16 - 16) * 8);
      v = *reinterpret_cast<const short8v*>(srcp);
    }
    int dbyte = r * 512 + ((c16 * 16) ^ ((r & 7) << 4));
    *reinterpret_cast<short8v*>(reinterpret_cast<char*>(As) + dbyte) = v;
  }
  __syncthreads();
  const int lane = tid & 63;
  const int rbase = (tid >> 6) * 16;
  const int arow = rbase + (lane & 15);
  const int axor = (arow & 7) << 4;
  const short8v* Wp8 = reinterpret_cast<const short8v*>(Wp);
  float4v acc[8];
#pragma unroll
  for (int f = 0; f < 8; ++f) acc[f] = {0.f, 0.f, 0.f, 0.f};
#pragma unroll
  for (int ks = 0; ks < 8; ++ks) {
    int abyte = arow * 512 + ((ks * 64 + (lane >> 4) * 16) ^ axor);
    short8v a = *reinterpret_cast<const short8v*>(reinterpret_cast<const char*>(As) + abyte);
#pragma unroll
    for (int f = 0; f < 8; ++f) {
      short8v bf = Wp8[(ks * 8 + f) * 64 + lane];
      acc[f] = __builtin_amdgcn_mfma_f32_16x16x32_bf16(a, bf, acc[f], 0, 0, 0);
    }
  }
  const int col_lo = lane & 15;
  const int rq = (lane >> 4) * 4;
#pragma unroll
  for (int f = 0; f < 8; ++f) {
    int col = f * 16 + col_lo;
    float bias = b[col];
#pragma unroll
    for (int r = 0; r < 4; ++r) {
      int row = row0 + rbase + rq + r;
      if (row < nrows) {
        float vv = fmaxf(acc[f][r] + bias, 0.f);
        h[(size_t)row * 128 + col] = f2bf(vv);
      }
    }
  }
}

// ---------------- layer2 MFMA GEMM: out = [mean2|h]@Wp2 + b2, fp32 out ----------------
__global__ __launch_bounds__(256) void k_mfma2(const ushort* __restrict__ meanb,
                                               const ushort* __restrict__ rootb,
                                               const ushort* __restrict__ Wp,
                                               const float* __restrict__ b,
                                               float* __restrict__ out, int nrows) {
  __shared__ __align__(16) ushort As[64 * 256];
  const int tid = threadIdx.x;
  const int row0 = blockIdx.x * 64;
#pragma unroll
  for (int i = 0; i < 8; ++i) {
    int c = tid + i * 256;
    int r = c >> 5;
    int c16 = c & 31;
    int grow = row0 + r;
    short8v v = {0, 0, 0, 0, 0, 0, 0, 0};
    if (grow < nrows) {
      const ushort* srcp = (c16 < 16) ? (meanb + (size_t)grow * 128 + c16 * 8)
                                      : (rootb + (size_t)grow * 128 + (c16 - 16) * 8);
      v = *reinterpret_cast<const short8v*>(srcp);
    }
    int dbyte = r * 512 + ((c16 * 16) ^ ((r & 7) << 4));
    *reinterpret_cast<short8v*>(reinterpret_cast<char*>(As) + dbyte) = v;
  }
  __syncthreads();
  const int lane = tid & 63;
  const int rbase = (tid >> 6) * 16;
  const int arow = rbase + (lane & 15);
  const int axor = (arow & 7) << 4;
  const short8v* Wp8 = reinterpret_cast<const short8v*>(Wp);
  float4v acc[3];
#pragma unroll
  for (int f = 0; f < 3; ++f) acc[f] = {0.f, 0.f, 0.f, 0.f};
#pragma unroll
  for (int ks = 0; ks < 8; ++ks) {
    int abyte = arow * 512 + ((ks * 64 + (lane >> 4) * 16) ^ axor);
    short8v a = *reinterpret_cast<const short8v*>(reinterpret_cast<const char*>(As) + abyte);
#pragma unroll
    for (int f = 0; f < 3; ++f) {
      short8v bf = Wp8[(ks * 3 + f) * 64 + lane];
      acc[f] = __builtin_amdgcn_mfma_f32_16x16x32_bf16(a, bf, acc[f], 0, 0, 0);
    }
  }
  const int col_lo = lane & 15;
  const int rq = (lane >> 4) * 4;
#pragma unroll
  for (int f = 0; f < 3; ++f) {
    int col = f * 16 + col_lo;
    if (col < CLSN) {
      float bias = b[col];
#pragma unroll
      for (int r = 0; r < 4; ++r) {
        int row = row0 + rbase + rq + r;
        if (row < nrows) out[(size_t)row * CLSN + col] = acc[f][r] + bias;
      }
    }
  }
}

extern "C" void kernel_launch(void* const* d_in, const int* in_sizes, int n_in,
                              void* d_out, int out_size, void* d_ws, size_t ws_size,
                              hipStream_t stream) {
  const float* x = (const float*)d_in[0];
  const int* ei = (const int*)d_in[1];
  const float* Wl1 = (const float*)d_in[2];
  const float* Wr1 = (const float*)d_in[3];
  const float* b1 = (const float*)d_in[4];
  const float* Wl2 = (const float*)d_in[5];
  const float* Wr2 = (const float*)d_in[6];
  const float* b2 = (const float*)d_in[7];
  float* out = (float*)d_out;

  const int n = in_sizes[0] / F;
  const int E = in_sizes[1] / 2;
  const int* src = ei;
  const int* dst = ei + E;

  const int nfine = (n + 511) >> 9;  // 196

  size_t off = 0;
  auto alloc = [&](size_t bytes) {
    size_t cur = off;
    off = (off + bytes + 255) & ~(size_t)255;
    return cur;
  };
  char* w = (char*)d_ws;
  int* offsets = (int*)(w + alloc((size_t)(n + 1) * 4));
  int* srcs = (int*)(w + alloc((size_t)E * 4));
  int* fcur = (int*)(w + alloc(NFINE_MAX * 4));
  int* fbase = (int*)(w + alloc((NFINE_MAX + 1) * 4));
  ushort* xb = (ushort*)(w + alloc((size_t)n * F * 2));
  ushort* hb = (ushort*)(w + alloc((size_t)n * F * 2));
  ushort* meanb = (ushort*)(w + alloc((size_t)n * F * 2));
  ushort* Wp1 = (ushort*)(w + alloc(32768 * 2));
  ushort* Wp2 = (ushort*)(w + alloc(12288 * 2));
  (void)ws_size;
  // pairs aliases meanb (dead until first aggregate); needs nfine*PCAP*4 ~ 8MB < 25.6MB
  uint* pairs = (uint*)meanb;

  // casts / weight packing
  k_cast<<<(n * 32 + 255) / 256, 256, 0, stream>>>(x, xb, n * 32);
  k_pack_w1<<<16, 256, 0, stream>>>(Wl1, Wr1, Wp1);
  k_pack_w2<<<6, 256, 0, stream>>>(Wl2, Wr2, Wp2);

  // binned CSR build (one-pass tiled radix partition)
  k_init_fcur<<<1, 256, 0, stream>>>(fcur, nfine);
  k_partition<<<(E + TILE - 1) / TILE, 256, 0, stream>>>(src, dst, fcur, pairs, E);
  k_scan_fine<<<1, 256, 0, stream>>>(fcur, fbase, nfine, E);
  k_local_scatter<<<nfine, 256, 0, stream>>>(pairs, fcur, fbase, offsets, srcs, n, E);

  // layer 1
  k_aggregate<<<(n * 64 + 255) / 256, 256, 0, stream>>>(xb, offsets, srcs, meanb, n);
  k_mfma1<<<(n + 63) / 64, 256, 0, stream>>>(meanb, xb, Wp1, b1, hb, n);

  // layer 2
  k_aggregate<<<(n * 64 + 255) / 256, 256, 0, stream>>>(hb, offsets, srcs, meanb, n);
  k_mfma2<<<(n + 63) / 64, 256, 0, stream>>>(meanb, hb, Wp2, b2, out, n);
}

// Round 7
// 217.293 us; speedup vs baseline: 3.0404x; 1.0889x over previous
//
#include <hip/hip_runtime.h>

#define F 128
#define CLSN 40
#define NFINE_MAX 256
#define PCAP 10240
#define TILE 4096
#define STAGE_CAP 10240

typedef __attribute__((ext_vector_type(8))) short short8v;
typedef __attribute__((ext_vector_type(4))) float float4v;

static __device__ inline ushort f2bf(float f) {
  uint u = __float_as_uint(f);
  uint r = (u + 0x7FFFu + ((u >> 16) & 1u)) >> 16;
  return (ushort)r;
}
static __device__ inline float bfLo(uint u) { return __uint_as_float(u << 16); }
static __device__ inline float bfHi(uint u) { return __uint_as_float(u & 0xFFFF0000u); }

// ---------------- casts / packing ----------------
__global__ __launch_bounds__(256) void k_cast(const float* __restrict__ in,
                                              ushort* __restrict__ outb, int nelem4) {
  int i = blockIdx.x * 256 + threadIdx.x;
  if (i < nelem4) {
    float4 v = reinterpret_cast<const float4*>(in)[i];
    ushort4 o;
    o.x = f2bf(v.x); o.y = f2bf(v.y); o.z = f2bf(v.z); o.w = f2bf(v.w);
    reinterpret_cast<ushort4*>(outb)[i] = o;
  }
}

// pack [Wl1;Wr1] (256x128) into MFMA B-frag order: Wp[((ks*8+f)*64+lane)*8+j]
__global__ __launch_bounds__(256) void k_pack_w1(const float* __restrict__ Wl,
                                                 const float* __restrict__ Wr,
                                                 ushort* __restrict__ Wp) {
  int t = blockIdx.x * 256 + threadIdx.x;
  if (t >= 4096) return;
  int lane = t & 63, f = (t >> 6) & 7, ks = t >> 9;
  int col = f * 16 + (lane & 15);
  int k0 = ks * 32 + (lane >> 4) * 8;
#pragma unroll
  for (int j = 0; j < 8; ++j) {
    int k = k0 + j;
    float w = (k < 128) ? Wl[k * 128 + col] : Wr[(k - 128) * 128 + col];
    Wp[t * 8 + j] = f2bf(w);
  }
}

// pack Wl2 and Wr2 (each 128x40, pad cols to 48) as K=128 frags: 4ks x 3f
__global__ __launch_bounds__(256) void k_pack_w2pair(const float* __restrict__ Wl,
                                                     const float* __restrict__ Wr,
                                                     ushort* __restrict__ Wpl,
                                                     ushort* __restrict__ Wpr) {
  int t = blockIdx.x * 256 + threadIdx.x;
  if (t >= 1536) return;
  const float* W = (t < 768) ? Wl : Wr;
  ushort* Wp = (t < 768) ? Wpl : Wpr;
  int tt = (t < 768) ? t : t - 768;  // FIX: 767 is not a pow2-1 mask
  int lane = tt & 63, rem = tt >> 6;
  int f = rem % 3, ks = rem / 3;
  int col = f * 16 + (lane & 15);
  int k0 = ks * 32 + (lane >> 4) * 8;
#pragma unroll
  for (int j = 0; j < 8; ++j) {
    int k = k0 + j;
    float w = (col < CLSN) ? W[k * CLSN + col] : 0.f;
    Wp[tt * 8 + j] = f2bf(w);
  }
}

// ---------------- one-pass tiled radix partition into fine buckets ----------------
__global__ void k_init_fcur(int* __restrict__ fcur, int nfine) {
  int i = blockIdx.x * 256 + threadIdx.x;
  if (i < nfine) fcur[i] = i * PCAP;
}

__global__ __launch_bounds__(256) void k_partition(const int* __restrict__ src,
                                                   const int* __restrict__ dst,
                                                   int* __restrict__ fcur,
                                                   uint* __restrict__ pairs, int E) {
  __shared__ int hh[NFINE_MAX];
  __shared__ int bb[NFINE_MAX];
  __shared__ unsigned char ebkt[TILE];
  __shared__ ushort dlow[TILE];
  const int tid = threadIdx.x;
  const int tile0 = blockIdx.x * TILE;
  const int lim = min(TILE, E - tile0);
  for (int i = tid; i < NFINE_MAX; i += 256) hh[i] = 0;
  __syncthreads();
  for (int i = tid; i < lim; i += 256) {
    int d = dst[tile0 + i];
    int b = d >> 9;
    ebkt[i] = (unsigned char)b;
    dlow[i] = (ushort)(d & 511);
    atomicAdd(&hh[b], 1);
  }
  __syncthreads();
  for (int i = tid; i < NFINE_MAX; i += 256) {
    int c = hh[i];
    bb[i] = c ? atomicAdd(&fcur[i], c) : 0;
    hh[i] = 0;  // reuse as local cursor
  }
  __syncthreads();
  for (int i = tid; i < lim; i += 256) {
    int b = ebkt[i];
    int r = atomicAdd(&hh[b], 1);
    uint p = (uint)src[tile0 + i] | ((uint)dlow[i] << 17);
    pairs[bb[b] + r] = p;
  }
}

__global__ __launch_bounds__(256) void k_scan_fine(const int* __restrict__ fcur,
                                                   int* __restrict__ fbase,
                                                   int nfine, int E) {
  __shared__ int s[256];
  int tid = threadIdx.x;
  int v = (tid < nfine) ? (fcur[tid] - tid * PCAP) : 0;
  s[tid] = v;
  __syncthreads();
  for (int d = 1; d < 256; d <<= 1) {
    int u = (tid >= d) ? s[tid - d] : 0;
    __syncthreads();
    s[tid] += u;
    __syncthreads();
  }
  if (tid < nfine) fbase[tid] = s[tid] - v;
  if (tid == 0) fbase[nfine] = E;
}

__global__ __launch_bounds__(256) void k_local_scatter(const uint* __restrict__ pairs,
                                                       const int* __restrict__ fcur,
                                                       const int* __restrict__ fbase,
                                                       int* __restrict__ offsets,
                                                       int* __restrict__ srcs,
                                                       int n, int E) {
  __shared__ int s_cnt[512];
  __shared__ int s_scan[512];
  __shared__ int s_stage[STAGE_CAP];
  const int b = blockIdx.x, tid = threadIdx.x;
  const int node0 = b << 9;
  const int pbase = b * PCAP;
  const int ebase = fbase[b];
  const int ecnt = fcur[b] - pbase;
  s_cnt[tid] = 0;
  s_cnt[tid + 256] = 0;
  __syncthreads();
  for (int i = tid; i < ecnt; i += 256) atomicAdd(&s_cnt[pairs[pbase + i] >> 17], 1);
  __syncthreads();
  s_scan[tid] = s_cnt[tid];
  s_scan[tid + 256] = s_cnt[tid + 256];
  __syncthreads();
  for (int d = 1; d < 512; d <<= 1) {
    int v0 = (tid >= d) ? s_scan[tid - d] : 0;
    int v1 = (tid + 256 >= d) ? s_scan[tid + 256 - d] : 0;
    __syncthreads();
    s_scan[tid] += v0;
    s_scan[tid + 256] += v1;
    __syncthreads();
  }
  int e0 = s_scan[tid] - s_cnt[tid];
  int e1 = s_scan[tid + 256] - s_cnt[tid + 256];
  if (node0 + tid < n) offsets[node0 + tid] = ebase + e0;
  if (node0 + tid + 256 < n) offsets[node0 + tid + 256] = ebase + e1;
  if (b == gridDim.x - 1 && tid == 0) offsets[n] = E;
  __syncthreads();
  s_cnt[tid] = e0;
  s_cnt[tid + 256] = e1;
  __syncthreads();
  for (int i = tid; i < ecnt; i += 256) {
    uint p = pairs[pbase + i];
    int v = (int)(p >> 17);
    int s = (int)(p & 0x1FFFFu);
    int pos = atomicAdd(&s_cnt[v], 1);
    if (pos < STAGE_CAP) s_stage[pos] = s;
    else srcs[ebase + pos] = s;
  }
  __syncthreads();
  int lim = min(ecnt, STAGE_CAP);
  for (int i = tid; i < lim; i += 256) srcs[ebase + i] = s_stage[i];
}

// ---------------- aggregation: 2 nodes per wave, half-wave per node ----------------
// x version: rows are 128 bf16 (256B); lane cl holds uint2 = features 4cl..4cl+3
__global__ __launch_bounds__(256) void k_agg_x(const ushort* __restrict__ feat,
                                               const int* __restrict__ offsets,
                                               const int* __restrict__ srcs,
                                               ushort* __restrict__ mean, int n) {
  int wid = (blockIdx.x * 256 + threadIdx.x) >> 6;
  int lane = threadIdx.x & 63;
  int sub = lane >> 5, cl = lane & 31;
  int node = wid * 2 + sub;
  if (node >= n) return;
  const uint2* fp = reinterpret_cast<const uint2*>(feat);
  int beg = offsets[node], end = offsets[node + 1];
  float a0 = 0.f, a1 = 0.f, a2 = 0.f, a3 = 0.f;
  int sbase = sub * 32;
  for (int chunk = beg; chunk < end; chunk += 32) {
    int cnt = min(32, end - chunk);
    int s = (cl < cnt) ? srcs[chunk + cl] : 0;
    int k = 0;
    for (; k + 7 < cnt; k += 8) {
      int r0 = __shfl(s, sbase + k), r1 = __shfl(s, sbase + k + 1);
      int r2 = __shfl(s, sbase + k + 2), r3 = __shfl(s, sbase + k + 3);
      int r4 = __shfl(s, sbase + k + 4), r5 = __shfl(s, sbase + k + 5);
      int r6 = __shfl(s, sbase + k + 6), r7 = __shfl(s, sbase + k + 7);
      uint2 v0 = fp[(size_t)r0 * 32 + cl];
      uint2 v1 = fp[(size_t)r1 * 32 + cl];
      uint2 v2 = fp[(size_t)r2 * 32 + cl];
      uint2 v3 = fp[(size_t)r3 * 32 + cl];
      uint2 v4 = fp[(size_t)r4 * 32 + cl];
      uint2 v5 = fp[(size_t)r5 * 32 + cl];
      uint2 v6 = fp[(size_t)r6 * 32 + cl];
      uint2 v7 = fp[(size_t)r7 * 32 + cl];
      a0 += bfLo(v0.x) + bfLo(v1.x) + bfLo(v2.x) + bfLo(v3.x) +
            bfLo(v4.x) + bfLo(v5.x) + bfLo(v6.x) + bfLo(v7.x);
      a1 += bfHi(v0.x) + bfHi(v1.x) + bfHi(v2.x) + bfHi(v3.x) +
            bfHi(v4.x) + bfHi(v5.x) + bfHi(v6.x) + bfHi(v7.x);
      a2 += bfLo(v0.y) + bfLo(v1.y) + bfLo(v2.y) + bfLo(v3.y) +
            bfLo(v4.y) + bfLo(v5.y) + bfLo(v6.y) + bfLo(v7.y);
      a3 += bfHi(v0.y) + bfHi(v1.y) + bfHi(v2.y) + bfHi(v3.y) +
            bfHi(v4.y) + bfHi(v5.y) + bfHi(v6.y) + bfHi(v7.y);
    }
    for (; k < cnt; ++k) {
      int r0 = __shfl(s, sbase + k);
      uint2 v0 = fp[(size_t)r0 * 32 + cl];
      a0 += bfLo(v0.x); a1 += bfHi(v0.x);
      a2 += bfLo(v0.y); a3 += bfHi(v0.y);
    }
  }
  int dg = end - beg;
  float inv = dg > 0 ? 1.f / (float)dg : 0.f;
  uint lo = (uint)f2bf(a0 * inv) | ((uint)f2bf(a1 * inv) << 16);
  uint hi = (uint)f2bf(a2 * inv) | ((uint)f2bf(a3 * inv) << 16);
  reinterpret_cast<uint2*>(mean)[(size_t)node * 32 + cl] = make_uint2(lo, hi);
}

// p version: rows are 64 bf16 (128B); lane cl holds uint = features 2cl,2cl+1.
// output m is fp32, 64-col stride.
__global__ __launch_bounds__(256) void k_agg_p(const ushort* __restrict__ p,
                                               const int* __restrict__ offsets,
                                               const int* __restrict__ srcs,
                                               float* __restrict__ m, int n) {
  int wid = (blockIdx.x * 256 + threadIdx.x) >> 6;
  int lane = threadIdx.x & 63;
  int sub = lane >> 5, cl = lane & 31;
  int node = wid * 2 + sub;
  if (node >= n) return;
  const uint* pp = reinterpret_cast<const uint*>(p);
  int beg = offsets[node], end = offsets[node + 1];
  float a0 = 0.f, a1 = 0.f;
  int sbase = sub * 32;
  for (int chunk = beg; chunk < end; chunk += 32) {
    int cnt = min(32, end - chunk);
    int s = (cl < cnt) ? srcs[chunk + cl] : 0;
    int k = 0;
    for (; k + 7 < cnt; k += 8) {
      int r0 = __shfl(s, sbase + k), r1 = __shfl(s, sbase + k + 1);
      int r2 = __shfl(s, sbase + k + 2), r3 = __shfl(s, sbase + k + 3);
      int r4 = __shfl(s, sbase + k + 4), r5 = __shfl(s, sbase + k + 5);
      int r6 = __shfl(s, sbase + k + 6), r7 = __shfl(s, sbase + k + 7);
      uint v0 = pp[(size_t)r0 * 32 + cl];
      uint v1 = pp[(size_t)r1 * 32 + cl];
      uint v2 = pp[(size_t)r2 * 32 + cl];
      uint v3 = pp[(size_t)r3 * 32 + cl];
      uint v4 = pp[(size_t)r4 * 32 + cl];
      uint v5 = pp[(size_t)r5 * 32 + cl];
      uint v6 = pp[(size_t)r6 * 32 + cl];
      uint v7 = pp[(size_t)r7 * 32 + cl];
      a0 += bfLo(v0) + bfLo(v1) + bfLo(v2) + bfLo(v3) +
            bfLo(v4) + bfLo(v5) + bfLo(v6) + bfLo(v7);
      a1 += bfHi(v0) + bfHi(v1) + bfHi(v2) + bfHi(v3) +
            bfHi(v4) + bfHi(v5) + bfHi(v6) + bfHi(v7);
    }
    for (; k < cnt; ++k) {
      int r0 = __shfl(s, sbase + k);
      uint v0 = pp[(size_t)r0 * 32 + cl];
      a0 += bfLo(v0); a1 += bfHi(v0);
    }
  }
  int dg = end - beg;
  float inv = dg > 0 ? 1.f / (float)dg : 0.f;
  reinterpret_cast<float2*>(m)[(size_t)node * 32 + cl] = make_float2(a0 * inv, a1 * inv);
}

// ---------------- layer1 MFMA GEMM: h = relu([mean|x]@Wp1 + b1), bf16 out ------------
__global__ __launch_bounds__(256) void k_mfma1(const ushort* __restrict__ meanb,
                                               const ushort* __restrict__ rootb,
                                               const ushort* __restrict__ Wp,
                                               const float* __restrict__ b,
                                               ushort* __restrict__ h, int nrows) {
  __shared__ __align__(16) ushort As[64 * 256];  // 32KB, XOR-swizzled
  const int tid = threadIdx.x;
  const int row0 = blockIdx.x * 64;
#pragma unroll
  for (int i = 0; i < 8; ++i) {
    int c = tid + i * 256;
    int r = c >> 5;
    int c16 = c & 31;
    int grow = row0 + r;
    short8v v = {0, 0, 0, 0, 0, 0, 0, 0};
    if (grow < nrows) {
      const ushort* srcp = (c16 < 16) ? (meanb + (size_t)grow * 128 + c16 * 8)
                                      : (rootb + (size_t)grow * 128 + (c16 - 16) * 8);
      v = *reinterpret_cast<const short8v*>(srcp);
    }
    int dbyte = r * 512 + ((c16 * 16) ^ ((r & 7) << 4));
    *reinterpret_cast<short8v*>(reinterpret_cast<char*>(As) + dbyte) = v;
  }
  __syncthreads();
  const int lane = tid & 63;
  const int rbase = (tid >> 6) * 16;
  const int arow = rbase + (lane & 15);
  const int axor = (arow & 7) << 4;
  const short8v* Wp8 = reinterpret_cast<const short8v*>(Wp);
  float4v acc[8];
#pragma unroll
  for (int f = 0; f < 8; ++f) acc[f] = {0.f, 0.f, 0.f, 0.f};
#pragma unroll
  for (int ks = 0; ks < 8; ++ks) {
    int abyte = arow * 512 + ((ks * 64 + (lane >> 4) * 16) ^ axor);
    short8v a = *reinterpret_cast<const short8v*>(reinterpret_cast<const char*>(As) + abyte);
#pragma unroll
    for (int f = 0; f < 8; ++f) {
      short8v bf = Wp8[(ks * 8 + f) * 64 + lane];
      acc[f] = __builtin_amdgcn_mfma_f32_16x16x32_bf16(a, bf, acc[f], 0, 0, 0);
    }
  }
  const int col_lo = lane & 15;
  const int rq = (lane >> 4) * 4;
#pragma unroll
  for (int f = 0; f < 8; ++f) {
    int col = f * 16 + col_lo;
    float bias = b[col];
#pragma unroll
    for (int r = 0; r < 4; ++r) {
      int row = row0 + rbase + rq + r;
      if (row < nrows) {
        float vv = fmaxf(acc[f][r] + bias, 0.f);
        h[(size_t)row * 128 + col] = f2bf(vv);
      }
    }
  }
}

// ---------------- layer2 projection: p = h@Wl2 (K=128, 48 real cols, 64-col rows) ----
__global__ __launch_bounds__(256) void k_proj2(const ushort* __restrict__ hb,
                                               const ushort* __restrict__ Wp,
                                               ushort* __restrict__ p, int nrows) {
  __shared__ __align__(16) ushort As[64 * 128];  // 16KB
  const int tid = threadIdx.x;
  const int row0 = blockIdx.x * 64;
#pragma unroll
  for (int i = 0; i < 4; ++i) {
    int c = tid + i * 256;  // 1024 16B-chunks
    int r = c >> 4;
    int c16 = c & 15;
    int grow = row0 + r;
    short8v v = {0, 0, 0, 0, 0, 0, 0, 0};
    if (grow < nrows) v = *reinterpret_cast<const short8v*>(hb + (size_t)grow * 128 + c16 * 8);
    int dbyte = r * 256 + ((c16 * 16) ^ ((r & 7) << 4));
    *reinterpret_cast<short8v*>(reinterpret_cast<char*>(As) + dbyte) = v;
  }
  __syncthreads();
  const int lane = tid & 63;
  const int rbase = (tid >> 6) * 16;
  const int arow = rbase + (lane & 15);
  const int axor = (arow & 7) << 4;
  const short8v* Wp8 = reinterpret_cast<const short8v*>(Wp);
  float4v acc[3];
#pragma unroll
  for (int f = 0; f < 3; ++f) acc[f] = {0.f, 0.f, 0.f, 0.f};
#pragma unroll
  for (int ks = 0; ks < 4; ++ks) {
    int abyte = arow * 256 + ((ks * 64 + (lane >> 4) * 16) ^ axor);
    short8v a = *reinterpret_cast<const short8v*>(reinterpret_cast<const char*>(As) + abyte);
#pragma unroll
    for (int f = 0; f < 3; ++f) {
      short8v bf = Wp8[(ks * 3 + f) * 64 + lane];
      acc[f] = __builtin_amdgcn_mfma_f32_16x16x32_bf16(a, bf, acc[f], 0, 0, 0);
    }
  }
  const int col_lo = lane & 15;
  const int rq = (lane >> 4) * 4;
#pragma unroll
  for (int f = 0; f < 3; ++f) {
    int col = f * 16 + col_lo;
#pragma unroll
    for (int r = 0; r < 4; ++r) {
      int row = row0 + rbase + rq + r;
      if (row < nrows) p[(size_t)row * 64 + col] = f2bf(acc[f][r]);
    }
  }
  // zero cols 48..63
#pragma unroll
  for (int r = 0; r < 4; ++r) {
    int row = row0 + rbase + rq + r;
    if (row < nrows) p[(size_t)row * 64 + 48 + col_lo] = 0;
  }
}

// ---------------- layer2 root: out = h@Wr2 + m + b2 (fp32 out, 40 cols) ----------------
__global__ __launch_bounds__(256) void k_root2(const ushort* __restrict__ hb,
                                               const ushort* __restrict__ Wp,
                                               const float* __restrict__ b,
                                               const float* __restrict__ m,
                                               float* __restrict__ out, int nrows) {
  __shared__ __align__(16) ushort As[64 * 128];
  const int tid = threadIdx.x;
  const int row0 = blockIdx.x * 64;
#pragma unroll
  for (int i = 0; i < 4; ++i) {
    int c = tid + i * 256;
    int r = c >> 4;
    int c16 = c & 15;
    int grow = row0 + r;
    short8v v = {0, 0, 0, 0, 0, 0, 0, 0};
    if (grow < nrows) v = *reinterpret_cast<const short8v*>(hb + (size_t)grow * 128 + c16 * 8);
    int dbyte = r * 256 + ((c16 * 16) ^ ((r & 7) << 4));
    *reinterpret_cast<short8v*>(reinterpret_cast<char*>(As) + dbyte) = v;
  }
  __syncthreads();
  const int lane = tid & 63;
  const int rbase = (tid >> 6) * 16;
  const int arow = rbase + (lane & 15);
  const int axor = (arow & 7) << 4;
  const short8v* Wp8 = reinterpret_cast<const short8v*>(Wp);
  float4v acc[3];
#pragma unroll
  for (int f = 0; f < 3; ++f) acc[f] = {0.f, 0.f, 0.f, 0.f};
#pragma unroll
  for (int ks = 0; ks < 4; ++ks) {
    int abyte = arow * 256 + ((ks * 64 + (lane >> 4) * 16) ^ axor);
    short8v a = *reinterpret_cast<const short8v*>(reinterpret_cast<const char*>(As) + abyte);
#pragma unroll
    for (int f = 0; f < 3; ++f) {
      short8v bf = Wp8[(ks * 3 + f) * 64 + lane];
      acc[f] = __builtin_amdgcn_mfma_f32_16x16x32_bf16(a, bf, acc[f], 0, 0, 0);
    }
  }
  const int col_lo = lane & 15;
  const int rq = (lane >> 4) * 4;
#pragma unroll
  for (int f = 0; f < 3; ++f) {
    int col = f * 16 + col_lo;
    if (col < CLSN) {
      float bias = b[col];
#pragma unroll
      for (int r = 0; r < 4; ++r) {
        int row = row0 + rbase + rq + r;
        if (row < nrows)
          out[(size_t)row * CLSN + col] = acc[f][r] + bias + m[(size_t)row * 64 + col];
      }
    }
  }
}

extern "C" void kernel_launch(void* const* d_in, const int* in_sizes, int n_in,
                              void* d_out, int out_size, void* d_ws, size_t ws_size,
                              hipStream_t stream) {
  const float* x = (const float*)d_in[0];
  const int* ei = (const int*)d_in[1];
  const float* Wl1 = (const float*)d_in[2];
  const float* Wr1 = (const float*)d_in[3];
  const float* b1 = (const float*)d_in[4];
  const float* Wl2 = (const float*)d_in[5];
  const float* Wr2 = (const float*)d_in[6];
  const float* b2 = (const float*)d_in[7];
  float* out = (float*)d_out;

  const int n = in_sizes[0] / F;
  const int E = in_sizes[1] / 2;
  const int* src = ei;
  const int* dst = ei + E;

  const int nfine = (n + 511) >> 9;  // 196

  size_t off = 0;
  auto alloc = [&](size_t bytes) {
    size_t cur = off;
    off = (off + bytes + 255) & ~(size_t)255;
    return cur;
  };
  char* w = (char*)d_ws;
  int* offsets = (int*)(w + alloc((size_t)(n + 1) * 4));
  int* srcs = (int*)(w + alloc((size_t)E * 4));
  int* fcur = (int*)(w + alloc(NFINE_MAX * 4));
  int* fbase = (int*)(w + alloc((NFINE_MAX + 1) * 4));
  ushort* xb = (ushort*)(w + alloc((size_t)n * F * 2));
  ushort* hb = (ushort*)(w + alloc((size_t)n * F * 2));
  ushort* meanb = (ushort*)(w + alloc((size_t)n * F * 2));
  ushort* Wp1 = (ushort*)(w + alloc(32768 * 2));
  ushort* Wp2l = (ushort*)(w + alloc(6144 * 2));
  ushort* Wp2r = (ushort*)(w + alloc(6144 * 2));
  (void)ws_size;
  // aliases: pairs (CSR build) and p64 (layer2 projection) live in meanb's region
  // (dead at those times); m64 (fp32, N*64) lives in xb's region (dead after mfma1).
  uint* pairs = (uint*)meanb;
  ushort* p64 = meanb;        // N*64 bf16 = half of meanb region
  float* m64 = (float*)xb;    // N*64 f32 = exactly xb region size

  // casts / weight packing
  k_cast<<<(n * 32 + 255) / 256, 256, 0, stream>>>(x, xb, n * 32);
  k_pack_w1<<<16, 256, 0, stream>>>(Wl1, Wr1, Wp1);
  k_pack_w2pair<<<6, 256, 0, stream>>>(Wl2, Wr2, Wp2l, Wp2r);

  // binned CSR build (one-pass tiled radix partition)
  k_init_fcur<<<1, 256, 0, stream>>>(fcur, nfine);
  k_partition<<<(E + TILE - 1) / TILE, 256, 0, stream>>>(src, dst, fcur, pairs, E);
  k_scan_fine<<<1, 256, 0, stream>>>(fcur, fbase, nfine, E);
  k_local_scatter<<<nfine, 256, 0, stream>>>(pairs, fcur, fbase, offsets, srcs, n, E);

  // layer 1: mean(x) -> h = relu([mean|x]@W1 + b1)
  k_agg_x<<<(n + 7) / 8, 256, 0, stream>>>(xb, offsets, srcs, meanb, n);
  k_mfma1<<<(n + 63) / 64, 256, 0, stream>>>(meanb, xb, Wp1, b1, hb, n);

  // layer 2 (projection-first): p = h@Wl2; m = mean(p); out = h@Wr2 + m + b2
  k_proj2<<<(n + 63) / 64, 256, 0, stream>>>(hb, Wp2l, p64, n);
  k_agg_p<<<(n + 7) / 8, 256, 0, stream>>>(p64, offsets, srcs, m64, n);
  k_root2<<<(n + 63) / 64, 256, 0, stream>>>(hb, Wp2r, b2, m64, out, n);
}